// Round 1
// baseline (187.302 us; speedup 1.0000x reference)
//
#include <hip/hip_runtime.h>

// LRN_19705309954750 — cross-channel banded LRN on [B=64, C=128, H=56, W=56] fp32.
// y[c] = sum_{d=-8..8} x[(c+d)%128]^2 ; out = x * (y*ALPHA/17 + 1)^(-0.75)
//
// R5 post-mortem: traffic ideal (62+100 MB) but hbm 2.4 TB/s, VALUBusy 10%,
// occupancy 22%, VGPR=72 -> latency-bound with ~1 load in flight per wave
// (ring design consumes each fresh load in the same iteration; compiler kept
// a minimal register budget and could not pipeline).
// R6: chunked recompute with BATCHED loads. Each thread owns one float4
// column x 8 output channels: issue 24 independent dwordx4 loads (c0-8 ..
// c0+15 mod 128) back-to-back (~24 KB in flight per wave), then sliding-
// window sum entirely in registers. 12544 one-wave blocks (49 waves/CU of
// work, 4x R5). Cache-side 3x halo re-read is L1/L2/L3-absorbed (input+output
// = 205 MB < 256 MB L3), so HBM traffic stays ~ideal. __launch_bounds__(64,4)
// grants a 128-VGPR budget so the 24-load batch stays resident (~110 VGPRs).

#define B_DIM 64
#define C_DIM 128
#define HW_DIM (56 * 56)        // 3136
#define HW4 (HW_DIM / 4)        // 784 float4 columns per plane
#define NCOL4 (B_DIM * HW4)     // 50176 float4 columns
#define CH 8                    // output channels per thread
#define PLANES (CH + 16)        // 24 input planes touched per chunk

__device__ __forceinline__ float pow_m075(float t) {
    // t in [1, ~1.01]; HW log2 + exp2 (~1 ulp each) — far inside 0.108 absmax
    return __builtin_amdgcn_exp2f(-0.75f * __builtin_amdgcn_logf(t));
}

__global__ __launch_bounds__(64, 4) void lrn_kernel(const float4* __restrict__ x,
                                                    float4* __restrict__ out) {
    const float kAlphaOverR = 0.001f / 17.0f;

    const int col4 = blockIdx.x * 64 + threadIdx.x;   // [0, NCOL4)
    const int b    = col4 / HW4;
    const int hw4  = col4 - b * HW4;
    const int c0   = blockIdx.y * CH;                 // chunk start channel

    const float4* base = x + ((size_t)b * C_DIM) * HW4 + hw4;   // chan stride = HW4
    float4* obase      = out + ((size_t)b * C_DIM) * HW4 + hw4;

    // ---- 24 independent loads, issued back-to-back (deep vmcnt pipeline) ----
    float4 v[PLANES];
#pragma unroll
    for (int j = 0; j < PLANES; ++j) {
        const int ch = (c0 + j - 8 + C_DIM) & (C_DIM - 1);
        v[j] = base[(size_t)ch * HW4];
    }

    // ---- window sum for first output channel (buffer idx 0..16) ----
    float sx = 0.f, sy = 0.f, sz = 0.f, sw = 0.f;
#pragma unroll
    for (int j = 0; j < 17; ++j) {
        sx = fmaf(v[j].x, v[j].x, sx);
        sy = fmaf(v[j].y, v[j].y, sy);
        sz = fmaf(v[j].z, v[j].z, sz);
        sw = fmaf(v[j].w, v[j].w, sw);
    }

    // ---- slide across the 8 output channels of this chunk ----
#pragma unroll
    for (int i = 0; i < CH; ++i) {
        const float4 xc = v[8 + i];                   // channel c0+i (numerator)
        float4 o;
        o.x = xc.x * pow_m075(fmaf(sx, kAlphaOverR, 1.0f));
        o.y = xc.y * pow_m075(fmaf(sy, kAlphaOverR, 1.0f));
        o.z = xc.z * pow_m075(fmaf(sz, kAlphaOverR, 1.0f));
        o.w = xc.w * pow_m075(fmaf(sw, kAlphaOverR, 1.0f));
        obase[(size_t)(c0 + i) * HW4] = o;

        if (i < CH - 1) {                             // slide window: +sq[i+17] -sq[i]
            const float4 a = v[17 + i];
            const float4 d = v[i];
            sx += a.x * a.x - d.x * d.x;
            sy += a.y * a.y - d.y * d.y;
            sz += a.z * a.z - d.z * d.z;
            sw += a.w * a.w - d.w * d.w;
        }
    }
}

extern "C" void kernel_launch(void* const* d_in, const int* in_sizes, int n_in,
                              void* d_out, int out_size, void* d_ws, size_t ws_size,
                              hipStream_t stream) {
    const float4* x = (const float4*)d_in[0];   // [64,128,56,56] fp32
    // d_in[1] (inhiMat) is a constant circulant band — computed analytically, unused.
    float4* out = (float4*)d_out;

    // 784 column-blocks x 16 channel-chunks, 64-thread (1-wave) blocks:
    // 12544 waves = 49 waves/CU of work; each wave has 24 loads in flight.
    dim3 grid(NCOL4 / 64, C_DIM / CH);
    lrn_kernel<<<grid, 64, 0, stream>>>(x, out);
}

// Round 2
// 185.696 us; speedup vs baseline: 1.0086x; 1.0086x over previous
//
#include <hip/hip_runtime.h>

// LRN_19705309954750 — cross-channel banded LRN on [B=64, C=128, H=56, W=56] fp32.
// y[c] = sum_{d=-8..8} x[(c+d)%128]^2 ; out = x * (y*ALPHA/17 + 1)^(-0.75)
//
// R6 post-mortem: compiler SANK the 24-load batch (VGPR=48, not ~110) — the
// deep pipeline never existed; BW stuck at 2.45 TB/s. Also cache-side traffic
// was 3x-amplified (24 planes / 8 outputs) = 411 MB / 66us = 6.2 TB/s ~= the
// achievable fabric ceiling.
// R7: (1) SEGC=32 channels/thread -> amplification 3.0x -> 1.5x (257 MB
// cache-side); (2) all 48 float2 plane-loads issued up front followed by
// __builtin_amdgcn_sched_barrier(0) -- a hard fence the compiler cannot sink
// loads across, forcing the 96 data VGPRs live and ~24 KB/wave in flight;
// (3) __launch_bounds__(64,3) caps VGPR at ~168 so no spill risk.
// Grid: 1568 col-blocks x 4 channel-segs = 6272 waves = 24.5/CU.

#define B_DIM 64
#define C_DIM 128
#define HW_DIM (56 * 56)        // 3136
#define HW2 (HW_DIM / 2)        // 1568 float2 columns per plane
#define NCOL2 (B_DIM * HW2)     // 100352 float2 columns
#define NSEG 4
#define SEGC (C_DIM / NSEG)     // 32 channels per thread
#define PLANES (SEGC + 16)      // 48 input planes touched per segment

__device__ __forceinline__ float pow_m075(float t) {
    // t in [1, ~1.01]; HW log2 + exp2 (~1 ulp each) — far inside 0.108 absmax
    return __builtin_amdgcn_exp2f(-0.75f * __builtin_amdgcn_logf(t));
}

__global__ __launch_bounds__(64, 3) void lrn_kernel(const float2* __restrict__ x,
                                                    float2* __restrict__ out) {
    const float kAlphaOverR = 0.001f / 17.0f;

    const int col = blockIdx.x * 64 + threadIdx.x;   // [0, NCOL2)
    const int b   = col / HW2;
    const int hw2 = col - b * HW2;
    const int c0  = blockIdx.y * SEGC;               // segment start channel

    const float2* base = x + ((size_t)b * C_DIM) * HW2 + hw2;   // chan stride = HW2
    float2* obase      = out + ((size_t)b * C_DIM) * HW2 + hw2;

    // ---- 48 independent loads, issued back-to-back; fence keeps them batched ----
    float2 v[PLANES];
#pragma unroll
    for (int j = 0; j < PLANES; ++j) {
        const int ch = (c0 + j - 8 + C_DIM) & (C_DIM - 1);
        v[j] = base[(size_t)ch * HW2];
    }
    __builtin_amdgcn_sched_barrier(0);   // loads may NOT sink past this point

    // ---- window sum for first output channel (buffer idx 0..16) ----
    float sx = 0.f, sy = 0.f;
#pragma unroll
    for (int j = 0; j < 17; ++j) {
        sx = fmaf(v[j].x, v[j].x, sx);
        sy = fmaf(v[j].y, v[j].y, sy);
    }

    // ---- slide across the 32 output channels of this segment ----
#pragma unroll
    for (int i = 0; i < SEGC; ++i) {
        const float2 xc = v[8 + i];                  // channel c0+i (numerator)
        float2 o;
        o.x = xc.x * pow_m075(fmaf(sx, kAlphaOverR, 1.0f));
        o.y = xc.y * pow_m075(fmaf(sy, kAlphaOverR, 1.0f));
        obase[(size_t)(c0 + i) * HW2] = o;

        if (i < SEGC - 1) {                          // slide window: +sq[i+17] -sq[i]
            const float2 a = v[17 + i];
            const float2 d = v[i];
            sx += a.x * a.x - d.x * d.x;
            sy += a.y * a.y - d.y * d.y;
        }
    }
}

extern "C" void kernel_launch(void* const* d_in, const int* in_sizes, int n_in,
                              void* d_out, int out_size, void* d_ws, size_t ws_size,
                              hipStream_t stream) {
    const float2* x = (const float2*)d_in[0];   // [64,128,56,56] fp32
    // d_in[1] (inhiMat) is a constant circulant band — computed analytically, unused.
    float2* out = (float2*)d_out;

    // 1568 column-blocks x 4 channel-segments, 64-thread (1-wave) blocks:
    // 6272 waves = 24.5 waves/CU; each wave issues 48 loads (24 KB) in flight.
    dim3 grid(NCOL2 / 64, NSEG);
    lrn_kernel<<<grid, 64, 0, stream>>>(x, out);
}